// Round 2
// baseline (406.852 us; speedup 1.0000x reference)
//
#include <hip/hip_runtime.h>
#include <stdint.h>

// GriddingDistance fwd, R7. Post-mortem of R6: all sort intermediates are
// L3-resident (256 MB Infinity Cache), so traffic shuffling was neutral; the
// ~165 us of kernel time is the 6-dispatch sort STRUCTURE (hist+3 scans+
// scatter ~100 us) + accum's 45 us write floor + ~222 us harness poison tax.
// R7 deletes the counting sort entirely: direct bump-allocation into per-bin
// buckets. cnt[] is 32 KB (L2-hot); 2.44M u32 atomicAdds over 8192 addresses
// = ~300-deep chains running in parallel across L2 channels (~5-12 us).
// [The old "global atomics capped ~20G/s" verdict was for 16.8M float RMWs
// missing L2 on the 256 MB output - different regime.] Pipeline: memset(32KB)
// -> scatter_direct -> accum. CAP=4096/bin (mean 298; overflow needs ~14x
// local over-density - impossible for uniform input; clamped defensively).

constexpr int R    = 128;
constexpr int R3c  = R * R * R;
constexpr int BPG  = 256;            // bins per grid: 8 x 8 x 4 (16,16,32 regions)
constexpr int NBLK = 512;            // scatter blocks
constexpr int BLKT = 512;            // threads per scatter block
constexpr int CAP  = 4096;           // records per bin bucket
constexpr int MAXBINS = 8192;

// ws layout (byte offsets); harness ws = 1 GiB
constexpr size_t WS_CNT    = 0;               // NBINS*4 = 32 KB
constexpr size_t WS_BUCKET = 1u << 20;        // NBINS*CAP*8 = 268 MB

typedef float f4v __attribute__((ext_vector_type(4)));

// ---- quantization: v = (p/128 + 0.5)*128 == p + 64 (<=1 ulp), vq = rn(v*2^14),
// clamped so ix = vq>>14 <= 126. All binning/weights derive from vq.
__device__ __forceinline__ uint32_t quant1(float p) {
    const float S = 16384.0f;                  // 2^14
    const uint32_t QMAX = (126u << 14) | 16383u;
    float v = p + 64.0f;
    return min(__float2uint_rn(fmaxf(v, 0.0f) * S), QMAX);
}

__device__ __forceinline__ uint2 pack_rec(uint32_t xq, uint32_t yq, uint32_t zq) {
    return make_uint2(xq | (yq << 21), (yq >> 11) | (zq << 10));
}
__device__ __forceinline__ void unpack_rec(uint2 r, uint32_t& xq, uint32_t& yq, uint32_t& zq) {
    xq = r.x & 0x1FFFFFu;
    yq = (r.x >> 21) | ((r.y & 0x3FFu) << 11);
    zq = (r.y >> 10) & 0x1FFFFFu;
}

__device__ __forceinline__ void load_point(
    const float* __restrict__ pred, const float* __restrict__ gt,
    int i, int total1, int n1, int n2, int B,
    float& px, float& py, float& pz, int& cb)
{
    const float* p;
    if (i < total1) { p = pred + (size_t)i * 3; cb = i / n1; }
    else { int j = i - total1; p = gt + (size_t)j * 3; cb = B + j / n2; }
    px = p[0]; py = p[1]; pz = p[2];
}

// region bounds from quantized cell coords
__device__ __forceinline__ void region_range(uint32_t xq, uint32_t yq, uint32_t zq,
                                             int& rx0, int& rx1, int& ry0, int& ry1,
                                             int& rz0, int& rz1)
{
    int ix = xq >> 14, iy = yq >> 14, iz = zq >> 14;
    rx0 = ix >> 4; rx1 = (ix + 1) >> 4;
    ry0 = iy >> 4; ry1 = (iy + 1) >> 4;
    rz0 = iz >> 5; rz1 = (iz + 1) >> 5;
}

// ---------------- pass 1: direct bump-allocated record scatter ----------------
__global__ __launch_bounds__(BLKT) void scatter_direct(
    const float* __restrict__ pred, const float* __restrict__ gt,
    int total1, int P, int n1, int n2, int B, int ppb, int vec4ok,
    uint32_t* __restrict__ cnt, uint2* __restrict__ bucket)
{
    int s = blockIdx.x * ppb, e = min(s + ppb, P);
    if (vec4ok) {
        // block range entirely inside pred or gt; 4-point groups, 3x float4 loads
        bool isgt = (s >= total1);
        const float* src = isgt ? gt + (size_t)(s - total1) * 3
                                : pred + (size_t)s * 3;
        const int n = isgt ? n2 : n1;
        const int cb0 = isgt ? B : 0;
        const int loff = isgt ? total1 : 0;
        const float4* src4 = (const float4*)src;
        int ngrp = (e - s) >> 2;
        for (int g = threadIdx.x; g < ngrp; g += BLKT) {
            float4 a = src4[g * 3 + 0];
            float4 b4 = src4[g * 3 + 1];
            float4 c4 = src4[g * 3 + 2];
            int li = (s + g * 4) - loff;
            int hbase = (cb0 + li / n) * BPG;
            float xs[4] = {a.x, a.w, b4.z, c4.y};
            float ys[4] = {a.y, b4.x, b4.w, c4.z};
            float zs[4] = {a.z, b4.y, c4.x, c4.w};
            #pragma unroll
            for (int q = 0; q < 4; ++q) {
                uint32_t xq = quant1(xs[q]), yq = quant1(ys[q]), zq = quant1(zs[q]);
                uint2 rec = pack_rec(xq, yq, zq);
                int rx0, rx1, ry0, ry1, rz0, rz1;
                region_range(xq, yq, zq, rx0, rx1, ry0, ry1, rz0, rz1);
                for (int aa = rx0; aa <= rx1; ++aa)
                    for (int bb = ry0; bb <= ry1; ++bb)
                        for (int cc = rz0; cc <= rz1; ++cc) {
                            int bin = hbase + (aa << 5) + (bb << 2) + cc;
                            uint32_t slot = atomicAdd(&cnt[bin], 1u);
                            if (slot < (uint32_t)CAP)
                                bucket[(size_t)bin * CAP + slot] = rec;
                        }
            }
        }
    } else {
        for (int i = s + threadIdx.x; i < e; i += BLKT) {
            float px, py, pz; int cb;
            load_point(pred, gt, i, total1, n1, n2, B, px, py, pz, cb);
            uint32_t xq = quant1(px), yq = quant1(py), zq = quant1(pz);
            uint2 rec = pack_rec(xq, yq, zq);
            int rx0, rx1, ry0, ry1, rz0, rz1;
            region_range(xq, yq, zq, rx0, rx1, ry0, ry1, rz0, rz1);
            int base = cb * BPG;
            for (int a = rx0; a <= rx1; ++a)
                for (int b = ry0; b <= ry1; ++b)
                    for (int c = rz0; c <= rz1; ++c) {
                        int bin = base + (a << 5) + (b << 2) + c;
                        uint32_t slot = atomicAdd(&cnt[bin], 1u);
                        if (slot < (uint32_t)CAP)
                            bucket[(size_t)bin * CAP + slot] = rec;
                    }
        }
    }
}

// ---------------- pass 2: per-region LDS accumulate + nontemporal 128B stores ----------------
__global__ __launch_bounds__(256) void accum_kernel(
    const uint32_t* __restrict__ cnt, const uint2* __restrict__ bucket,
    float* __restrict__ out)
{
    __shared__ float tile[16 * 16 * 32];           // 32 KB
    int bin = blockIdx.x;
    int cb = bin >> 8;
    int region = bin & 255;
    int rx = region >> 5, ry = (region >> 2) & 7, rz = region & 3;

    float4* t4 = (float4*)tile;
    for (int t = threadIdx.x; t < 2048; t += 256)
        t4[t] = make_float4(0.f, 0.f, 0.f, 0.f);
    __syncthreads();

    uint32_t e = min(cnt[bin], (uint32_t)CAP);
    const uint2* recs = bucket + (size_t)bin * CAP;
    const float FQ = 6.103515625e-05f;             // 2^-14
    for (uint32_t r = threadIdx.x; r < e; r += 256) {
        uint32_t xq, yq, zq;
        unpack_rec(recs[r], xq, yq, zq);
        int ix = xq >> 14, iy = yq >> 14, iz = zq >> 14;
        float fx = (float)(xq & 16383u) * FQ;
        float fy = (float)(yq & 16383u) * FQ;
        float fz = (float)(zq & 16383u) * FQ;
        float wx[2] = {1.0f - fx, fx};
        float wy[2] = {1.0f - fy, fy};
        float wz[2] = {1.0f - fz, fz};
        #pragma unroll
        for (int dx = 0; dx < 2; ++dx) {
            int cx = ix + dx;
            if ((cx >> 4) != rx) continue;
            #pragma unroll
            for (int dy = 0; dy < 2; ++dy) {
                int cy = iy + dy;
                if ((cy >> 4) != ry) continue;
                float wxy = wx[dx] * wy[dy];
                #pragma unroll
                for (int dz = 0; dz < 2; ++dz) {
                    int cz = iz + dz;
                    if ((cz >> 5) != rz) continue;
                    atomicAdd(&tile[(((cx & 15) << 4) + (cy & 15)) * 32 + (cz & 31)],
                              wxy * wz[dz]);
                }
            }
        }
    }
    __syncthreads();

    // full region store: each (X,Y) z-row is 32 floats = one 128 B line; output
    // is write-once streaming -> nontemporal, keep L2 for the record stream
    float* gout = out + (size_t)cb * R3c;
    for (int w = threadIdx.x; w < 2048; w += 256) {
        int lin = w * 4;
        int lx = lin >> 9, rem = lin & 511, ly = rem >> 5, lz = rem & 31;
        int X = rx * 16 + lx, Y = ry * 16 + ly, Z = rz * 32 + lz;
        f4v v = ((const f4v*)tile)[w];
        __builtin_nontemporal_store(v, (f4v*)&gout[((size_t)X * R + Y) * R + Z]);
    }
}

// ---------------- fallback (R1 path) ----------------
__device__ __forceinline__ void point_math_f(float px, float py, float pz,
                                             int& ix, int& iy, int& iz,
                                             float& fx, float& fy, float& fz)
{
    const float inv = 1.0f / 128.0f;
    float vx = (px * inv + 0.5f) * 128.0f;
    float vy = (py * inv + 0.5f) * 128.0f;
    float vz = (pz * inv + 0.5f) * 128.0f;
    float lx = floorf(vx), ly = floorf(vy), lz = floorf(vz);
    fx = vx - lx; fy = vy - ly; fz = vz - lz;
    ix = min(max((int)lx, 0), R - 2);
    iy = min(max((int)ly, 0), R - 2);
    iz = min(max((int)lz, 0), R - 2);
}

__global__ __launch_bounds__(256) void gridding_scatter(
    const float* __restrict__ cloud, float* __restrict__ grid,
    int total_pts, int n_per_batch)
{
    int idx = blockIdx.x * blockDim.x + threadIdx.x;
    if (idx >= total_pts) return;
    int b = idx / n_per_batch;
    const float* p = cloud + (size_t)idx * 3;
    int ix, iy, iz; float fx, fy, fz;
    point_math_f(p[0], p[1], p[2], ix, iy, iz, fx, fy, fz);
    float wx[2] = {1.0f - fx, fx};
    float wy[2] = {1.0f - fy, fy};
    float wz[2] = {1.0f - fz, fz};
    float* gb = grid + (size_t)b * R3c;
    #pragma unroll
    for (int dx = 0; dx < 2; ++dx)
        #pragma unroll
        for (int dy = 0; dy < 2; ++dy) {
            float wxy = wx[dx] * wy[dy];
            #pragma unroll
            for (int dz = 0; dz < 2; ++dz)
                atomicAdd(gb + ((size_t)(ix + dx) * R + (iy + dy)) * R + (iz + dz),
                          wxy * wz[dz]);
        }
}

extern "C" void kernel_launch(void* const* d_in, const int* in_sizes, int n_in,
                              void* d_out, int out_size, void* d_ws, size_t ws_size,
                              hipStream_t stream) {
    const float* pred = (const float*)d_in[0];
    const float* gt   = (const float*)d_in[1];
    float* out = (float*)d_out;

    int total1 = in_sizes[0] / 3;
    int total2 = in_sizes[1] / 3;
    int B  = out_size / (2 * R3c);   // 16
    int n1 = total1 / B;
    int n2 = total2 / B;
    int NBINS = 2 * B * BPG;         // 8192
    int P  = total1 + total2;
    int ppb = (P + NBLK - 1) / NBLK;

    size_t ws_need = WS_BUCKET + (size_t)NBINS * CAP * 8;
    if (ws_size < ws_need || NBINS > MAXBINS || NBINS % 256 != 0) {
        hipMemsetAsync(d_out, 0, (size_t)out_size * sizeof(float), stream);
        gridding_scatter<<<(total1 + 255) / 256, 256, 0, stream>>>(pred, out, total1, n1);
        gridding_scatter<<<(total2 + 255) / 256, 256, 0, stream>>>(
            gt, out + (size_t)B * R3c, total2, n2);
        return;
    }

    // fast vector path: every block fully inside one cloud, 4-point groups
    // never straddle a batch, all blocks full
    int vec4ok = (ppb % 4 == 0) && (total1 % ppb == 0) && (P % ppb == 0) &&
                 (n1 % 4 == 0) && (n2 % 4 == 0);

    uint32_t* cnt    = (uint32_t*)((char*)d_ws + WS_CNT);
    uint2*    bucket = (uint2*)((char*)d_ws + WS_BUCKET);

    hipMemsetAsync(cnt, 0, (size_t)NBINS * sizeof(uint32_t), stream);
    scatter_direct<<<NBLK, BLKT, 0, stream>>>(pred, gt, total1, P, n1, n2, B, ppb,
                                              vec4ok, cnt, bucket);
    accum_kernel<<<NBINS, 256, 0, stream>>>(cnt, bucket, out);
}

// Round 3
// 386.156 us; speedup vs baseline: 1.0536x; 1.0536x over previous
//
#include <hip/hip_runtime.h>
#include <stdint.h>

// GriddingDistance fwd, R8. Post-mortem R7: bump-allocation lost 14 us - the
// 268 MB bucket footprint (8B stores scattered over 8192x32KB stripes) blew
// L3 and pushed scatter/accum traffic to HBM. Sort structure (R5/R6 ~390us)
// restored. R8 insight: every sort block's 4096 points live in ONE
// (cloud,batch) -> only 256 bins, yet R6 kept 8192-bin LDS hists and scanned
// 512x8192 (97% structural zeros, ~28 MB of scan traffic). Compact hist to
// [512][256] u32 = 512 KB: pass A LDS = 1 KB (no batch divide at all), scans
// collapse to 2 tiny kernels (~1 MB traffic), pass C cursors = 1 KB LDS.
// 6 dispatches -> 5. Harness tax ~222 us (1 GiB ws poison ~170 meas + 268 MB
// out poison ~43); D's 268 MB output write floor = 42.5 us.

constexpr int R    = 128;
constexpr int R3c  = R * R * R;
constexpr int BPG  = 256;            // bins per (cloud,batch): 8 x 8 x 4 regions of 16x16x32
constexpr int NBLK = 512;            // sort blocks
constexpr int BLKT = 512;            // threads per sort block
constexpr int MAXB = 128;            // max batch count supported by ws layout

// ws layout (byte offsets); harness ws = 1 GiB
constexpr size_t WS_HIST = 0;                 // NBLK*BPG*4 = 512 KB
constexpr size_t WS_TOT  = 768u << 10;        // NBINS*4 (<= 256 KB)
constexpr size_t WS_BASE = 1u << 20;          // (NBINS+1)*4
constexpr size_t WS_QREC = 2u << 20;          // P*8 = 16 MB
constexpr size_t WS_REC  = 20u << 20;         // worst case 8P*8 = 128 MB

typedef float f4v __attribute__((ext_vector_type(4)));

// ---- quantization: v = (p/128 + 0.5)*128 == p + 64 (<=1 ulp), vq = rn(v*2^14),
// clamped so ix = vq>>14 <= 126. All binning/weights derive from vq.
__device__ __forceinline__ uint32_t quant1(float p) {
    const float S = 16384.0f;                  // 2^14
    const uint32_t QMAX = (126u << 14) | 16383u;
    float v = p + 64.0f;
    return min(__float2uint_rn(fmaxf(v, 0.0f) * S), QMAX);
}

__device__ __forceinline__ uint2 pack_rec(uint32_t xq, uint32_t yq, uint32_t zq) {
    return make_uint2(xq | (yq << 21), (yq >> 11) | (zq << 10));
}
__device__ __forceinline__ void unpack_rec(uint2 r, uint32_t& xq, uint32_t& yq, uint32_t& zq) {
    xq = r.x & 0x1FFFFFu;
    yq = (r.x >> 21) | ((r.y & 0x3FFu) << 11);
    zq = (r.y >> 10) & 0x1FFFFFu;
}

// local (within cloud,batch) region bounds from quantized cell coords
__device__ __forceinline__ void region_range(uint32_t xq, uint32_t yq, uint32_t zq,
                                             int& rx0, int& rx1, int& ry0, int& ry1,
                                             int& rz0, int& rz1)
{
    int ix = xq >> 14, iy = yq >> 14, iz = zq >> 14;
    rx0 = ix >> 4; rx1 = (ix + 1) >> 4;
    ry0 = iy >> 4; ry1 = (iy + 1) >> 4;
    rz0 = iz >> 5; rz1 = (iz + 1) >> 5;
}

// ---------------- pass A: compact LDS histogram + packed qrec emission ----------------
// precondition (checked host-side): each block's point range lies in ONE cloud
// and ONE batch; ppb % 4 == 0.
__global__ __launch_bounds__(BLKT) void bin_hist_qrec(
    const float* __restrict__ pred, const float* __restrict__ gt,
    int total1, int P, int ppb,
    uint32_t* __restrict__ hist, uint2* __restrict__ qrec)
{
    __shared__ uint32_t h[BPG];                    // 1 KB
    if (threadIdx.x < BPG) h[threadIdx.x] = 0;
    __syncthreads();

    int s = blockIdx.x * ppb;
    if (s < P) {
        int e = min(s + ppb, P);
        bool isgt = (s >= total1);
        const float* src = isgt ? gt + (size_t)(s - total1) * 3
                                : pred + (size_t)s * 3;
        const float4* src4 = (const float4*)src;
        int ngrp = (e - s) >> 2;
        for (int g = threadIdx.x; g < ngrp; g += BLKT) {
            float4 a  = src4[g * 3 + 0];
            float4 b4 = src4[g * 3 + 1];
            float4 c4 = src4[g * 3 + 2];
            float xs[4] = {a.x, a.w, b4.z, c4.y};
            float ys[4] = {a.y, b4.x, b4.w, c4.z};
            float zs[4] = {a.z, b4.y, c4.x, c4.w};
            uint2 rec[4];
            #pragma unroll
            for (int q = 0; q < 4; ++q) {
                uint32_t xq = quant1(xs[q]), yq = quant1(ys[q]), zq = quant1(zs[q]);
                rec[q] = pack_rec(xq, yq, zq);
                int rx0, rx1, ry0, ry1, rz0, rz1;
                region_range(xq, yq, zq, rx0, rx1, ry0, ry1, rz0, rz1);
                for (int aa = rx0; aa <= rx1; ++aa)
                    for (int bb = ry0; bb <= ry1; ++bb)
                        for (int cc = rz0; cc <= rz1; ++cc)
                            atomicAdd(&h[(aa << 5) + (bb << 2) + cc], 1u);
            }
            uint4* q4 = (uint4*)(qrec + (size_t)s + (size_t)g * 4);
            q4[0] = make_uint4(rec[0].x, rec[0].y, rec[1].x, rec[1].y);
            q4[1] = make_uint4(rec[2].x, rec[2].y, rec[3].x, rec[3].y);
        }
    }
    __syncthreads();
    if (threadIdx.x < BPG)
        hist[(size_t)blockIdx.x * BPG + threadIdx.x] = h[threadIdx.x];
}

// ---------------- scan 1: per-bin column scan over contributing blocks ----------------
// thread j (global bin): walk the blocks of its (cloud,batch) group in order,
// replacing counts with exclusive prefixes; write bin total.
__global__ __launch_bounds__(256) void scan1(
    uint32_t* __restrict__ hist, uint32_t* __restrict__ tot,
    int B, int nb1, int bpg1, int bpg2, int NBINS)
{
    int j = blockIdx.x * 256 + threadIdx.x;
    if (j >= NBINS) return;
    int cb = j >> 8, l = j & 255;
    int first = (cb < B) ? cb * bpg1 : nb1 + (cb - B) * bpg2;
    int cnt   = (cb < B) ? bpg1 : bpg2;
    uint32_t run = 0;
    for (int k = 0; k < cnt; ++k) {
        size_t idx = (size_t)(first + k) * BPG + l;
        uint32_t t = hist[idx];
        hist[idx] = run;
        run += t;
    }
    tot[j] = run;
}

// ---------------- scan 2: exclusive scan of bin totals ----------------
__global__ __launch_bounds__(256) void scan_base(
    const uint32_t* __restrict__ tot, uint32_t* __restrict__ base, int NBINS)
{
    __shared__ uint32_t part[256];
    int t = threadIdx.x;
    int chunk = NBINS / 256;
    uint32_t s = 0;
    for (int i = 0; i < chunk; ++i) s += tot[t * chunk + i];
    part[t] = s;
    __syncthreads();
    if (t == 0) {
        uint32_t run = 0;
        for (int i = 0; i < 256; ++i) { uint32_t v = part[i]; part[i] = run; run += v; }
    }
    __syncthreads();
    uint32_t run = part[t];
    for (int i = 0; i < chunk; ++i) {
        base[t * chunk + i] = run;
        run += tot[t * chunk + i];
    }
    if (t == 255) base[NBINS] = run;
}

// ---------------- pass C: deterministic record permute (reads qrec) ----------------
__global__ __launch_bounds__(BLKT) void bin_scatter_qrec(
    const uint2* __restrict__ qrec,
    int total1, int P, int n1, int n2, int B, int ppb,
    const uint32_t* __restrict__ hist, const uint32_t* __restrict__ base,
    uint2* __restrict__ records)
{
    int s = blockIdx.x * ppb;
    if (s >= P) return;
    // scalar per-block group id
    int cb = (s < total1) ? (s / n1) : (B + (s - total1) / n2);

    __shared__ uint32_t cur[BPG];                  // 1 KB
    if (threadIdx.x < BPG)
        cur[threadIdx.x] = base[cb * BPG + threadIdx.x] +
                           hist[(size_t)blockIdx.x * BPG + threadIdx.x];
    __syncthreads();

    int e = min(s + ppb, P);
    const uint4* qr4 = (const uint4*)(qrec + (size_t)s);
    int ngrp = (e - s) >> 2;
    for (int g = threadIdx.x; g < ngrp; g += BLKT) {
        uint4 q0 = qr4[2 * g];
        uint4 q1 = qr4[2 * g + 1];
        uint2 rec[4] = {make_uint2(q0.x, q0.y), make_uint2(q0.z, q0.w),
                        make_uint2(q1.x, q1.y), make_uint2(q1.z, q1.w)};
        #pragma unroll
        for (int q = 0; q < 4; ++q) {
            uint32_t xq, yq, zq;
            unpack_rec(rec[q], xq, yq, zq);
            int rx0, rx1, ry0, ry1, rz0, rz1;
            region_range(xq, yq, zq, rx0, rx1, ry0, ry1, rz0, rz1);
            for (int aa = rx0; aa <= rx1; ++aa)
                for (int b2 = ry0; b2 <= ry1; ++b2)
                    for (int cc = rz0; cc <= rz1; ++cc) {
                        uint32_t slot =
                            atomicAdd(&cur[(aa << 5) + (b2 << 2) + cc], 1u);
                        records[slot] = rec[q];
                    }
        }
    }
}

// ---------------- pass D: per-region LDS accumulate + nontemporal 128B stores ----------------
__global__ __launch_bounds__(256) void accum_kernel(
    const uint32_t* __restrict__ base, const uint2* __restrict__ records,
    float* __restrict__ out)
{
    __shared__ float tile[16 * 16 * 32];           // 32 KB
    int bin = blockIdx.x;
    int cb = bin >> 8;
    int region = bin & 255;
    int rx = region >> 5, ry = (region >> 2) & 7, rz = region & 3;

    float4* t4 = (float4*)tile;
    for (int t = threadIdx.x; t < 2048; t += 256)
        t4[t] = make_float4(0.f, 0.f, 0.f, 0.f);
    __syncthreads();

    uint32_t s = base[bin], e = base[bin + 1];
    const float FQ = 6.103515625e-05f;             // 2^-14
    for (uint32_t r = s + threadIdx.x; r < e; r += 256) {
        uint32_t xq, yq, zq;
        unpack_rec(records[r], xq, yq, zq);
        int ix = xq >> 14, iy = yq >> 14, iz = zq >> 14;
        float fx = (float)(xq & 16383u) * FQ;
        float fy = (float)(yq & 16383u) * FQ;
        float fz = (float)(zq & 16383u) * FQ;
        float wx[2] = {1.0f - fx, fx};
        float wy[2] = {1.0f - fy, fy};
        float wz[2] = {1.0f - fz, fz};
        #pragma unroll
        for (int dx = 0; dx < 2; ++dx) {
            int cx = ix + dx;
            if ((cx >> 4) != rx) continue;
            #pragma unroll
            for (int dy = 0; dy < 2; ++dy) {
                int cy = iy + dy;
                if ((cy >> 4) != ry) continue;
                float wxy = wx[dx] * wy[dy];
                #pragma unroll
                for (int dz = 0; dz < 2; ++dz) {
                    int cz = iz + dz;
                    if ((cz >> 5) != rz) continue;
                    atomicAdd(&tile[(((cx & 15) << 4) + (cy & 15)) * 32 + (cz & 31)],
                              wxy * wz[dz]);
                }
            }
        }
    }
    __syncthreads();

    // full region store: each (X,Y) z-row is 32 floats = one 128 B line; output
    // is write-once streaming -> nontemporal, keep L2 for the record stream
    float* gout = out + (size_t)cb * R3c;
    for (int w = threadIdx.x; w < 2048; w += 256) {
        int lin = w * 4;
        int lx = lin >> 9, rem = lin & 511, ly = rem >> 5, lz = rem & 31;
        int X = rx * 16 + lx, Y = ry * 16 + ly, Z = rz * 32 + lz;
        f4v v = ((const f4v*)tile)[w];
        __builtin_nontemporal_store(v, (f4v*)&gout[((size_t)X * R + Y) * R + Z]);
    }
}

// ---------------- fallback (R1 path) ----------------
__device__ __forceinline__ void point_math_f(float px, float py, float pz,
                                             int& ix, int& iy, int& iz,
                                             float& fx, float& fy, float& fz)
{
    const float inv = 1.0f / 128.0f;
    float vx = (px * inv + 0.5f) * 128.0f;
    float vy = (py * inv + 0.5f) * 128.0f;
    float vz = (pz * inv + 0.5f) * 128.0f;
    float lx = floorf(vx), ly = floorf(vy), lz = floorf(vz);
    fx = vx - lx; fy = vy - ly; fz = vz - lz;
    ix = min(max((int)lx, 0), R - 2);
    iy = min(max((int)ly, 0), R - 2);
    iz = min(max((int)lz, 0), R - 2);
}

__global__ __launch_bounds__(256) void gridding_scatter(
    const float* __restrict__ cloud, float* __restrict__ grid,
    int total_pts, int n_per_batch)
{
    int idx = blockIdx.x * blockDim.x + threadIdx.x;
    if (idx >= total_pts) return;
    int b = idx / n_per_batch;
    const float* p = cloud + (size_t)idx * 3;
    int ix, iy, iz; float fx, fy, fz;
    point_math_f(p[0], p[1], p[2], ix, iy, iz, fx, fy, fz);
    float wx[2] = {1.0f - fx, fx};
    float wy[2] = {1.0f - fy, fy};
    float wz[2] = {1.0f - fz, fz};
    float* gb = grid + (size_t)b * R3c;
    #pragma unroll
    for (int dx = 0; dx < 2; ++dx)
        #pragma unroll
        for (int dy = 0; dy < 2; ++dy) {
            float wxy = wx[dx] * wy[dy];
            #pragma unroll
            for (int dz = 0; dz < 2; ++dz)
                atomicAdd(gb + ((size_t)(ix + dx) * R + (iy + dy)) * R + (iz + dz),
                          wxy * wz[dz]);
        }
}

extern "C" void kernel_launch(void* const* d_in, const int* in_sizes, int n_in,
                              void* d_out, int out_size, void* d_ws, size_t ws_size,
                              hipStream_t stream) {
    const float* pred = (const float*)d_in[0];
    const float* gt   = (const float*)d_in[1];
    float* out = (float*)d_out;

    int total1 = in_sizes[0] / 3;
    int total2 = in_sizes[1] / 3;
    int B  = out_size / (2 * R3c);   // 16
    int n1 = total1 / B;
    int n2 = total2 / B;
    int NBINS = 2 * B * BPG;         // 8192
    int P  = total1 + total2;
    int ppb = (P + NBLK - 1) / NBLK;

    // fast path preconditions: every block fully inside one (cloud,batch),
    // 4-point groups never straddle, all sizes exact
    bool fastok = (ppb % 4 == 0) && (n1 % ppb == 0) && (n2 % ppb == 0) &&
                  (n1 > 0) && (n2 > 0) && (B > 0) && (B <= MAXB) &&
                  (NBINS % 256 == 0) &&
                  (total1 % n1 == 0) && (total2 % n2 == 0);
    size_t ws_need = WS_REC + (size_t)8 * P * 8;
    if (!fastok || ws_size < ws_need) {
        hipMemsetAsync(d_out, 0, (size_t)out_size * sizeof(float), stream);
        gridding_scatter<<<(total1 + 255) / 256, 256, 0, stream>>>(pred, out, total1, n1);
        gridding_scatter<<<(total2 + 255) / 256, 256, 0, stream>>>(
            gt, out + (size_t)B * R3c, total2, n2);
        return;
    }

    uint32_t* hist  = (uint32_t*)((char*)d_ws + WS_HIST);
    uint32_t* tot   = (uint32_t*)((char*)d_ws + WS_TOT);
    uint32_t* basep = (uint32_t*)((char*)d_ws + WS_BASE);
    uint2*    qrec  = (uint2*)((char*)d_ws + WS_QREC);
    uint2*    recs  = (uint2*)((char*)d_ws + WS_REC);

    int nb1  = total1 / ppb;         // blocks for pred
    int bpg1 = n1 / ppb;             // blocks per (pred,batch)
    int bpg2 = n2 / ppb;             // blocks per (gt,batch)

    bin_hist_qrec<<<NBLK, BLKT, 0, stream>>>(pred, gt, total1, P, ppb, hist, qrec);
    scan1<<<(NBINS + 255) / 256, 256, 0, stream>>>(hist, tot, B, nb1, bpg1, bpg2, NBINS);
    scan_base<<<1, 256, 0, stream>>>(tot, basep, NBINS);
    bin_scatter_qrec<<<NBLK, BLKT, 0, stream>>>(qrec, total1, P, n1, n2, B, ppb,
                                                hist, basep, recs);
    accum_kernel<<<NBINS, 256, 0, stream>>>(basep, recs, out);
}